// Round 9
// baseline (224.232 us; speedup 1.0000x reference)
//
#include <hip/hip_runtime.h>
#include <hip/hip_bf16.h>

#define HH 32
#define KVHN 8
#define HD 64
#define DMODEL 2048
#define SEQ 2048
#define BB 2
#define NTOK 4096     // BB*SEQ
#define DKV 512       // KVHN*HD
#define NQKV 3072     // DMODEL + 2*DKV

typedef __bf16 bf16x8 __attribute__((ext_vector_type(8)));
typedef __bf16 bf16x4 __attribute__((ext_vector_type(4)));
typedef float  f32x4  __attribute__((ext_vector_type(4)));

typedef const __attribute__((address_space(1))) void gvoid_t;
typedef __attribute__((address_space(3))) void lvoid_t;

__device__ inline void glds16(const void* g, void* l) {
  __builtin_amdgcn_global_load_lds((gvoid_t*)g, (lvoid_t*)l, 16, 0, 0);
}

__device__ inline f32x4 mfma16(bf16x8 a, bf16x8 b, f32x4 c) {
  return __builtin_amdgcn_mfma_f32_16x16x32_bf16(a, b, c, 0, 0, 0);
}

// 2^x via v_exp_f32 (glibc shadows __exp2f; this is the HW op directly)
__device__ inline float fast_exp2(float x) {
  float r;
  asm("v_exp_f32 %0, %1" : "=v"(r) : "v"(x));
  return r;
}

// ---------------- prep kernels ----------------

__global__ __launch_bounds__(256)
void k_cvt_hidden(const float* __restrict__ in, __bf16* __restrict__ out) {
  int i = (blockIdx.x * 256 + threadIdx.x) * 4;
  f32x4 v = *(const f32x4*)(in + i);
  bf16x4 o;
  o[0] = (__bf16)v[0]; o[1] = (__bf16)v[1]; o[2] = (__bf16)v[2]; o[3] = (__bf16)v[3];
  *(bf16x4*)(out + i) = o;
}

// T[n][k] = W[k][n], f32 -> bf16.  grid (N/32, K/32), block 256
__global__ __launch_bounds__(256)
void k_transpose_w(const float* __restrict__ W, __bf16* __restrict__ T, int K, int N) {
  __shared__ float tile[32][33];
  int n0 = blockIdx.x * 32, k0 = blockIdx.y * 32;
  int tx = threadIdx.x & 31, ty = threadIdx.x >> 5;
#pragma unroll
  for (int i = 0; i < 32; i += 8)
    tile[ty + i][tx] = W[(size_t)(k0 + ty + i) * N + n0 + tx];
  __syncthreads();
#pragma unroll
  for (int i = 0; i < 32; i += 8)
    T[(size_t)(n0 + ty + i) * K + k0 + tx] = (__bf16)tile[tx][ty + i];
}

// merged wk+wv transpose: z=0 -> wk, z=1 -> wv.  grid (16, 64, 2)
__global__ __launch_bounds__(256)
void k_transpose_kv(const float* __restrict__ WK, const float* __restrict__ WV,
                    __bf16* __restrict__ T) {
  __shared__ float tile[32][33];
  const float* W = blockIdx.z ? WV : WK;
  __bf16* Td = T + (size_t)(2048 + blockIdx.z * 512) * 2048;
  int n0 = blockIdx.x * 32, k0 = blockIdx.y * 32;
  int tx = threadIdx.x & 31, ty = threadIdx.x >> 5;
#pragma unroll
  for (int i = 0; i < 32; i += 8)
    tile[ty + i][tx] = W[(size_t)(k0 + ty + i) * 512 + n0 + tx];
  __syncthreads();
#pragma unroll
  for (int i = 0; i < 32; i += 8)
    Td[(size_t)(n0 + ty + i) * 2048 + k0 + tx] = (__bf16)tile[tx][ty + i];
}

// VT[b][c][s] = Vt[b*S+s][c] (bf16, compact V [NTOK][512]).  grid (16, 64, 2)
__global__ __launch_bounds__(256)
void k_transpose_v(const __bf16* __restrict__ Vt, __bf16* __restrict__ VT) {
  __shared__ __bf16 tile[32][33];
  int c0 = blockIdx.x * 32, s0 = blockIdx.y * 32, b = blockIdx.z;
  int tx = threadIdx.x & 31, ty = threadIdx.x >> 5;
#pragma unroll
  for (int i = 0; i < 32; i += 8)
    tile[ty + i][tx] = Vt[(size_t)(b * SEQ + s0 + ty + i) * DKV + c0 + tx];
  __syncthreads();
#pragma unroll
  for (int i = 0; i < 32; i += 8)
    VT[(size_t)(b * DKV + c0 + ty + i) * SEQ + s0 + tx] = tile[tx][ty + i];
}

// ---------------- pipelined GEMM: C = A[M][K] * BT[N][K]^T ----------------
// 128x128 tile, BK=32, 4 waves (2M x 2N, 64x64 each), 256 thr, 32KB LDS
// -> 4 blocks/CU co-resident (768-block QKV grid is ALL-resident).
// Counted-vmcnt prefetch; swizzled ds_read_b128; setprio MFMA.
// EPI==0: plain store to C.  EPI==1: fused QKV epilogue (per-head RMSNorm +
// RoPE, Q pre-scaled by 0.125*log2(e); writes Qr/Kr/Vt, C unused).

__device__ inline void stc(float* p, float v)  { *p = v; }
__device__ inline void stc(__bf16* p, float v) { *p = (__bf16)v; }

template <int EPI, typename CT>
__global__ __launch_bounds__(256, 4)
void k_gemm3(const __bf16* __restrict__ A, const __bf16* __restrict__ BT,
             CT* __restrict__ C, int M, int N, int K,
             const float* __restrict__ cosT, const float* __restrict__ sinT,
             const float* __restrict__ qw, const float* __restrict__ kw,
             __bf16* __restrict__ Qr, __bf16* __restrict__ Kr,
             __bf16* __restrict__ Vt) {
  __shared__ alignas(16) __bf16 Al[2][128 * 32];
  __shared__ alignas(16) __bf16 Bl[2][128 * 32];
  const int tid = threadIdx.x;
  const int wid = tid >> 6, lane = tid & 63, g = lane >> 4, r16 = lane & 15;
  const int wm = wid >> 1, wn = wid & 1;
  const int nbm = M >> 7, nbn = N >> 7;
  const int nwg = nbm * nbn;
  int id = blockIdx.x;
  id = (id & 7) * (nwg >> 3) + (id >> 3);   // XCD swizzle (nwg % 8 == 0 here)
  const int bm = id % nbm, bn = id / nbm;

  // staging: 2 A rows + 2 B rows per thread, source chunk XOR-swizzled
  const int sr1 = tid >> 2, sr2 = 64 + (tid >> 2);
  const int c1 = (((tid & 3) ^ (sr1 & 3) ^ ((sr1 >> 2) & 3))) * 8;
  const int c2 = (((tid & 3) ^ (sr2 & 3) ^ ((sr2 >> 2) & 3))) * 8;
  const __bf16* gA1 = A + (size_t)(bm * 128 + sr1) * K + c1;
  const __bf16* gA2 = A + (size_t)(bm * 128 + sr2) * K + c2;
  const __bf16* gB1 = BT + (size_t)(bn * 128 + sr1) * K + c1;
  const __bf16* gB2 = BT + (size_t)(bn * 128 + sr2) * K + c2;

  // fragment read offsets (same swizzle)
  int aoff[4], boff[4];
#pragma unroll
  for (int m = 0; m < 4; ++m) {
    int row = wm * 64 + m * 16 + r16;
    aoff[m] = row * 32 + (g ^ (row & 3) ^ ((row >> 2) & 3)) * 8;
  }
#pragma unroll
  for (int n = 0; n < 4; ++n) {
    int row = wn * 64 + n * 16 + r16;
    boff[n] = row * 32 + (g ^ (row & 3) ^ ((row >> 2) & 3)) * 8;
  }

  auto STAGE = [&](int sl, int kt) {
    const int ko = kt * 32;
    glds16(gA1 + ko, &Al[sl][tid * 8]);
    glds16(gA2 + ko, &Al[sl][2048 + tid * 8]);
    glds16(gB1 + ko, &Bl[sl][tid * 8]);
    glds16(gB2 + ko, &Bl[sl][2048 + tid * 8]);
  };

  f32x4 acc[4][4] = {};
  const int nk = K >> 5;

  STAGE(0, 0);
  for (int kt = 0; kt < nk; ++kt) {
    const int s = kt & 1;
    if (kt + 1 < nk) {
      STAGE(s ^ 1, kt + 1);
      asm volatile("s_waitcnt vmcnt(4)" ::: "memory");
    } else {
      asm volatile("s_waitcnt vmcnt(0)" ::: "memory");
    }
    __builtin_amdgcn_s_barrier();
    bf16x8 af[4], bfr[4];
#pragma unroll
    for (int m = 0; m < 4; ++m) af[m] = *(const bf16x8*)&Al[s][aoff[m]];
#pragma unroll
    for (int n = 0; n < 4; ++n) bfr[n] = *(const bf16x8*)&Bl[s][boff[n]];
    __builtin_amdgcn_s_setprio(1);
#pragma unroll
    for (int m = 0; m < 4; ++m)
#pragma unroll
      for (int n = 0; n < 4; ++n)
        acc[m][n] = mfma16(af[m], bfr[n], acc[m][n]);
    __builtin_amdgcn_s_setprio(0);
    __builtin_amdgcn_s_barrier();   // guard: all reads of slot s done before overwrite
  }

  if (EPI == 0) {
#pragma unroll
    for (int m = 0; m < 4; ++m) {
      int row = bm * 128 + wm * 64 + m * 16 + g * 4;
#pragma unroll
      for (int n = 0; n < 4; ++n) {
        int col = bn * 128 + wn * 64 + n * 16 + r16;
#pragma unroll
        for (int r = 0; r < 4; ++r)
          stc(&C[(size_t)(row + r) * N + col], acc[m][n][r]);
      }
    }
  } else {
    // fused QKV epilogue.  This wave's 64 cols = exactly one head (or V slice).
    const int colbase = bn * 128 + wn * 64;
    const float QSCALE = 0.18033688011112042f;   // 0.125 * log2(e)
    if (colbase < DMODEL + DKV) {
      const bool isq = colbase < DMODEL;
      const float* wp = isq ? qw : kw;
      const float qs = isq ? QSCALE : 1.0f;
      float w4[4];
#pragma unroll
      for (int n = 0; n < 4; ++n) w4[n] = wp[n * 16 + r16];
#pragma unroll
      for (int m = 0; m < 4; ++m) {
        const int rowm = bm * 128 + wm * 64 + m * 16 + g * 4;
        float ss[4];
#pragma unroll
        for (int r = 0; r < 4; ++r) {
          ss[r] = acc[m][0][r] * acc[m][0][r] + acc[m][1][r] * acc[m][1][r] +
                  acc[m][2][r] * acc[m][2][r] + acc[m][3][r] * acc[m][3][r];
#pragma unroll
          for (int mk = 1; mk < 16; mk <<= 1) ss[r] += __shfl_xor(ss[r], mk);
          ss[r] = rsqrtf(ss[r] * (1.0f / HD) + 1e-6f);
        }
#pragma unroll
        for (int r = 0; r < 4; ++r) {
          const int t = rowm + r;
          const int sidx = t & (SEQ - 1);
          const float inv_ = ss[r];
#pragma unroll
          for (int n = 0; n < 4; ++n) {
            const int d = n * 16 + r16;
            const float xn = acc[m][n][r] * inv_ * w4[n];
            const float xp = acc[m][n ^ 2][r] * inv_ * w4[n ^ 2];
            const float rot = (n < 2) ? -xp : xp;
            const float cv = cosT[sidx * HD + d], sv = sinT[sidx * HD + d];
            const float o = (xn * cv + rot * sv) * qs;
            if (isq) {
              const int hq = colbase >> 6;
              Qr[((size_t)t * HH + hq) * HD + d] = (__bf16)o;
            } else {
              const int kvh = (colbase - DMODEL) >> 6;
              Kr[((size_t)t * KVHN + kvh) * HD + d] = (__bf16)o;
            }
          }
        }
      }
    } else {
      const int vc0 = colbase - (DMODEL + DKV);
#pragma unroll
      for (int m = 0; m < 4; ++m) {
        const int rowm = bm * 128 + wm * 64 + m * 16 + g * 4;
#pragma unroll
        for (int n = 0; n < 4; ++n)
#pragma unroll
          for (int r = 0; r < 4; ++r)
            Vt[(size_t)(rowm + r) * DKV + vc0 + n * 16 + r16] = (__bf16)acc[m][n][r];
      }
    }
  }
}

// ---------------- flash attention (causal, GQA) ----------------
// grid: flat 512, block 512 (8 waves, 16 waves/CU at 2 blocks/CU).
// CONCURRENT PAIR: each block owns the complementary pair {15-j, j}
// (j = f&7) of 128-row q-tiles and processes them IN THE SAME kv loop:
// rb=0 = 16 rows of the heavy tile (15-j), rb=1 = 16 rows of the light
// tile (j).  The light tile's kv range (2j+2 tiles) is a PREFIX of the
// heavy's (32-2j), so one K/V staging stream serves both; kf/vf are read
// once per kv-iteration and feed both rb.  Iterations per block drop from
// 34 (sequential pair) to 32-2j (avg 25) while compute stays exactly 34
// units for every block -> balance preserved, ~26% fewer barrier drains,
// ~19% fewer LDS ops, 26% less K/V staging traffic.
// SWAPPED QK^T: sacc = mfma(kf, qf) gives S^T; lane(g,r16) holds
// S[kv=ks*16+g*4+r][q=r16] -> P store is 4x ds_write_b64 into row-major
// P[q][kv]; PV b128 read unchanged.  Denominator: one scalar per lane per
// rb, g-groups summed in epilogue (shfl_xor 16,32) + shfl redistribute.

__global__ __launch_bounds__(512)
void k_attn(const __bf16* __restrict__ Q, const __bf16* __restrict__ Kg,
            const __bf16* __restrict__ VT, __bf16* __restrict__ O) {
  __shared__ alignas(16) __bf16 Kl[2][64 * 64];
  __shared__ alignas(16) __bf16 Vl[2][64 * 64];
  __shared__ alignas(16) __bf16 Pl[8][16 * 72];
  const int f = blockIdx.x;
  const int b = f >> 8;
  const int h = (f & 255) >> 3;
  const int j = f & 7;
  const int kvh = h >> 2;
  const int tid = threadIdx.x, wid = tid >> 6, lane = tid & 63;
  const int g = lane >> 4, r16 = lane & 15;
  __bf16* Pw = Pl[wid];

  const int rr = lane >> 3;                 // row within wave's 8-row slab
  const int cc = (lane & 7) ^ rr;           // swizzled source chunk

  auto STAGE = [&](int buf, int kb) {
    const int krow = kb * 64 + wid * 8 + rr;
    glds16(&Kg[((size_t)(b * SEQ + krow) * KVHN + kvh) * HD + cc * 8],
           &Kl[buf][wid * 512]);
    const int d = wid * 8 + rr;
    glds16(&VT[(size_t)(b * DKV + kvh * HD + d) * SEQ + (size_t)kb * 64 + cc * 8],
           &Vl[buf][wid * 512]);
  };

  // two q-row bases: rb=0 -> heavy tile 15-j, rb=1 -> light tile j
  const int q0[2] = { (15 - j) * 128 + wid * 16, j * 128 + wid * 16 };
  const int ntile = 2 * (15 - j) + 2;

  bf16x8 qf[2][2];
#pragma unroll
  for (int rb = 0; rb < 2; ++rb)
#pragma unroll
    for (int h2 = 0; h2 < 2; ++h2)
      qf[rb][h2] = *(const bf16x8*)&Q[(((size_t)b * SEQ + q0[rb] + r16) * HH + h) * HD + h2 * 32 + g * 8];

  f32x4 acc[2][4] = {};
  float l_q[2] = {};   // per-lane partial denominator for q = q0[rb]+r16

  STAGE(0, 0);
  asm volatile("s_waitcnt vmcnt(0)" ::: "memory");
  __syncthreads();

  for (int kb = 0; kb < ntile; ++kb) {
    const int cur = kb & 1;
    if (kb + 1 < ntile) STAGE(cur ^ 1, kb + 1);   // prefetch next tile
    const __bf16* Kb = Kl[cur];
    const __bf16* Vb = Vl[cur];
    const bool act0 = (kb * 64 <= q0[0] + 15);    // heavy tile rows active
    const bool act1 = (kb * 64 <= q0[1] + 15);    // light tile rows active
    if (act0 || act1) {
      bf16x8 kf[4][2];
#pragma unroll
      for (int ks = 0; ks < 4; ++ks)
#pragma unroll
        for (int h2 = 0; h2 < 2; ++h2) {
          const int p = r16 + ks * 16;
          const int ch = (g + 4 * h2) ^ (p & 7);
          kf[ks][h2] = *(const bf16x8*)&Kb[p * 64 + ch * 8];
        }
      bf16x8 pf[2][2];
#pragma unroll
      for (int rb = 0; rb < 2; ++rb) {
        if (!(rb ? act1 : act0)) continue;
        const int qw = q0[rb];
        const bool needmask = (kb * 64 + 63 > qw);
        float svv[4][4];
        __builtin_amdgcn_s_setprio(1);
#pragma unroll
        for (int ks = 0; ks < 4; ++ks) {
          f32x4 sacc = {-12.f, -12.f, -12.f, -12.f};   // fixed max in C-init
          sacc = mfma16(kf[ks][0], qf[rb][0], sacc);   // SWAPPED: S^T
          sacc = mfma16(kf[ks][1], qf[rb][1], sacc);
#pragma unroll
          for (int r = 0; r < 4; ++r) svv[ks][r] = sacc[r];
        }
        __builtin_amdgcn_s_setprio(0);
        if (needmask) {
#pragma unroll
          for (int ks = 0; ks < 4; ++ks)
#pragma unroll
            for (int r = 0; r < 4; ++r) {
              int pg = kb * 64 + ks * 16 + g * 4 + r;  // kv (swapped)
              int qg = qw + r16;                       // q  (swapped)
              if (pg > qg) svv[ks][r] = -1e30f;
            }
        }
        // exp2 + packed b64 store into P[q=r16][kv]
#pragma unroll
        for (int ks = 0; ks < 4; ++ks) {
          bf16x4 pk;
#pragma unroll
          for (int r = 0; r < 4; ++r) {
            float p = fast_exp2(svv[ks][r]);
            l_q[rb] += p;
            pk[r] = (__bf16)p;
          }
          *(bf16x4*)&Pw[r16 * 72 + ks * 16 + g * 4] = pk;
        }
        pf[rb][0] = *(const bf16x8*)&Pw[r16 * 72 + g * 8];
        pf[rb][1] = *(const bf16x8*)&Pw[r16 * 72 + 32 + g * 8];
      }
      // PV: vf read once, shared by both rb
      __builtin_amdgcn_s_setprio(1);
#pragma unroll
      for (int nb = 0; nb < 4; ++nb) {
        const int d = r16 + nb * 16;
        const int ch0 = g ^ (d & 7), ch1 = (4 + g) ^ (d & 7);
        bf16x8 vf0 = *(const bf16x8*)&Vb[d * 64 + ch0 * 8];
        bf16x8 vf1 = *(const bf16x8*)&Vb[d * 64 + ch1 * 8];
        if (act0) {
          acc[0][nb] = mfma16(pf[0][0], vf0, acc[0][nb]);
          acc[0][nb] = mfma16(pf[0][1], vf1, acc[0][nb]);
        }
        if (act1) {
          acc[1][nb] = mfma16(pf[1][0], vf0, acc[1][nb]);
          acc[1][nb] = mfma16(pf[1][1], vf1, acc[1][nb]);
        }
      }
      __builtin_amdgcn_s_setprio(0);
    }
    asm volatile("s_waitcnt vmcnt(0)" ::: "memory");
    __syncthreads();
  }
  // epilogue: complete l over kv (sum 4 g-groups), redistribute, store
#pragma unroll
  for (int rb = 0; rb < 2; ++rb) {
    l_q[rb] += __shfl_xor(l_q[rb], 16);
    l_q[rb] += __shfl_xor(l_q[rb], 32);
    const float invq = 1.0f / l_q[rb];
    float inv[4];
#pragma unroll
    for (int r = 0; r < 4; ++r) inv[r] = __shfl(invq, g * 4 + r);
#pragma unroll
    for (int nb = 0; nb < 4; ++nb)
#pragma unroll
      for (int r = 0; r < 4; ++r)
        O[(((size_t)b * SEQ + q0[rb] + g * 4 + r) * HH + h) * HD + nb * 16 + r16] =
            (__bf16)(acc[rb][nb][r] * inv[r]);
  }
}

// ---------------- launch ----------------

extern "C" void kernel_launch(void* const* d_in, const int* in_sizes, int n_in,
                              void* d_out, int out_size, void* d_ws, size_t ws_size,
                              hipStream_t stream) {
  const float* hidden = (const float*)d_in[0];
  const float* cosT   = (const float*)d_in[1];
  const float* sinT   = (const float*)d_in[2];
  const float* wq     = (const float*)d_in[3];
  const float* wk     = (const float*)d_in[4];
  const float* wv     = (const float*)d_in[5];
  const float* wo     = (const float*)d_in[6];
  const float* qw     = (const float*)d_in[7];
  const float* kw     = (const float*)d_in[8];
  float* out = (float*)d_out;
  char* ws = (char*)d_ws;

  // workspace layout (64 MB, lifetime-aliased):
  __bf16* Abf  = (__bf16*)(ws);                      // [0,16M) hidden bf16; later Ob
  __bf16* Ob   = Abf;
  __bf16* WT   = (__bf16*)(ws + (16u << 20));        // [16,28M) qkv weights^T
  __bf16* Qr   = (__bf16*)(ws + (28u << 20));        // [28,44M) Q roped (log2 domain)
  __bf16* Kr   = (__bf16*)(ws + (44u << 20));        // [44,48M) K roped
  __bf16* Vtmp = (__bf16*)(ws + (48u << 20));        // [48,52M) V compact [NTOK][512]
  __bf16* VT   = (__bf16*)(ws + (52u << 20));        // [52,56M) V transposed
  __bf16* WoT  = (__bf16*)(ws + (56u << 20));        // [56,64M)

  k_cvt_hidden<<<8192, 256, 0, stream>>>(hidden, Abf);
  k_transpose_w<<<dim3(64, 64), 256, 0, stream>>>(wq, WT, 2048, 2048);
  k_transpose_kv<<<dim3(16, 64, 2), 256, 0, stream>>>(wk, wv, WT);
  k_transpose_w<<<dim3(64, 64), 256, 0, stream>>>(wo, WoT, 2048, 2048);

  k_gemm3<1, __bf16><<<768, 256, 0, stream>>>(Abf, WT, (__bf16*)nullptr,
      NTOK, NQKV, DMODEL, cosT, sinT, qw, kw, Qr, Kr, Vtmp);

  k_transpose_v<<<dim3(16, 64, 2), 256, 0, stream>>>(Vtmp, VT);

  k_attn<<<dim3(512), 512, 0, stream>>>(Qr, Kr, VT, Ob);

  k_gemm3<0, float><<<512, 256, 0, stream>>>(Ob, WoT, out,
      NTOK, DMODEL, DMODEL, nullptr, nullptr, nullptr, nullptr,
      nullptr, nullptr, nullptr);
}

// Round 10
// 194.295 us; speedup vs baseline: 1.1541x; 1.1541x over previous
//
#include <hip/hip_runtime.h>
#include <hip/hip_bf16.h>

#define HH 32
#define KVHN 8
#define HD 64
#define DMODEL 2048
#define SEQ 2048
#define BB 2
#define NTOK 4096     // BB*SEQ
#define DKV 512       // KVHN*HD
#define NQKV 3072     // DMODEL + 2*DKV

typedef __bf16 bf16x8 __attribute__((ext_vector_type(8)));
typedef __bf16 bf16x4 __attribute__((ext_vector_type(4)));
typedef float  f32x4  __attribute__((ext_vector_type(4)));

typedef const __attribute__((address_space(1))) void gvoid_t;
typedef __attribute__((address_space(3))) void lvoid_t;

__device__ inline void glds16(const void* g, void* l) {
  __builtin_amdgcn_global_load_lds((gvoid_t*)g, (lvoid_t*)l, 16, 0, 0);
}

__device__ inline f32x4 mfma16(bf16x8 a, bf16x8 b, f32x4 c) {
  return __builtin_amdgcn_mfma_f32_16x16x32_bf16(a, b, c, 0, 0, 0);
}

// 2^x via v_exp_f32 (glibc shadows __exp2f; this is the HW op directly)
__device__ inline float fast_exp2(float x) {
  float r;
  asm("v_exp_f32 %0, %1" : "=v"(r) : "v"(x));
  return r;
}

// ---------------- prep kernels ----------------

__global__ __launch_bounds__(256)
void k_cvt_hidden(const float* __restrict__ in, __bf16* __restrict__ out) {
  int i = (blockIdx.x * 256 + threadIdx.x) * 4;
  f32x4 v = *(const f32x4*)(in + i);
  bf16x4 o;
  o[0] = (__bf16)v[0]; o[1] = (__bf16)v[1]; o[2] = (__bf16)v[2]; o[3] = (__bf16)v[3];
  *(bf16x4*)(out + i) = o;
}

// T[n][k] = W[k][n], f32 -> bf16.  grid (N/32, K/32), block 256
__global__ __launch_bounds__(256)
void k_transpose_w(const float* __restrict__ W, __bf16* __restrict__ T, int K, int N) {
  __shared__ float tile[32][33];
  int n0 = blockIdx.x * 32, k0 = blockIdx.y * 32;
  int tx = threadIdx.x & 31, ty = threadIdx.x >> 5;
#pragma unroll
  for (int i = 0; i < 32; i += 8)
    tile[ty + i][tx] = W[(size_t)(k0 + ty + i) * N + n0 + tx];
  __syncthreads();
#pragma unroll
  for (int i = 0; i < 32; i += 8)
    T[(size_t)(n0 + ty + i) * K + k0 + tx] = (__bf16)tile[tx][ty + i];
}

// merged wk+wv transpose: z=0 -> wk, z=1 -> wv.  grid (16, 64, 2)
__global__ __launch_bounds__(256)
void k_transpose_kv(const float* __restrict__ WK, const float* __restrict__ WV,
                    __bf16* __restrict__ T) {
  __shared__ float tile[32][33];
  const float* W = blockIdx.z ? WV : WK;
  __bf16* Td = T + (size_t)(2048 + blockIdx.z * 512) * 2048;
  int n0 = blockIdx.x * 32, k0 = blockIdx.y * 32;
  int tx = threadIdx.x & 31, ty = threadIdx.x >> 5;
#pragma unroll
  for (int i = 0; i < 32; i += 8)
    tile[ty + i][tx] = W[(size_t)(k0 + ty + i) * 512 + n0 + tx];
  __syncthreads();
#pragma unroll
  for (int i = 0; i < 32; i += 8)
    Td[(size_t)(n0 + ty + i) * 2048 + k0 + tx] = (__bf16)tile[tx][ty + i];
}

// VT[b][c][s] = Vt[b*S+s][c] (bf16, compact V [NTOK][512]).  grid (16, 64, 2)
__global__ __launch_bounds__(256)
void k_transpose_v(const __bf16* __restrict__ Vt, __bf16* __restrict__ VT) {
  __shared__ __bf16 tile[32][33];
  int c0 = blockIdx.x * 32, s0 = blockIdx.y * 32, b = blockIdx.z;
  int tx = threadIdx.x & 31, ty = threadIdx.x >> 5;
#pragma unroll
  for (int i = 0; i < 32; i += 8)
    tile[ty + i][tx] = Vt[(size_t)(b * SEQ + s0 + ty + i) * DKV + c0 + tx];
  __syncthreads();
#pragma unroll
  for (int i = 0; i < 32; i += 8)
    VT[(size_t)(b * DKV + c0 + ty + i) * SEQ + s0 + tx] = tile[tx][ty + i];
}

// ---------------- pipelined GEMM: C = A[M][K] * BT[N][K]^T ----------------
// 128x128 tile, BK=32, 4 waves (2M x 2N, 64x64 each), 256 thr, 32KB LDS
// -> 4 blocks/CU co-resident.  Counted-vmcnt prefetch; setprio MFMA.
// LDS layout: ROW-PAIR lines.  Two 64B rows form one 128B line of 8 16B
// chunks; chunk slot = c8 ^ (pair&7) where c8 = (row&1)*4 + g.  This is
// the empirically conflict-free pattern (gemm8/round-4 measured 0
// SQ_LDS_BANK_CONFLICT with 128B-line XOR-8; the previous 64B-row XOR-4
// layout measured exactly 4 extra cycles per ds_read_b128 = 6.29M/dispatch).
// Staging stays linear in LDS (glds16 dest = tid*16B); the global SOURCE
// (row, col) per thread is the inverse permutation:
//   p = tid>>3, c8 = (tid&7) ^ (p&7), row = 2p + (c8>>2), col = (c8&3)*8.
// Fragment read offset for (row, g):
//   (row>>1)*64 + ((((row&1)<<2)|g) ^ ((row>>1)&7))*8.
// EPI==0: plain store to C.  EPI==1: fused QKV epilogue (per-head RMSNorm +
// RoPE, Q pre-scaled by 0.125*log2(e); writes Qr/Kr/Vt, C unused).

__device__ inline void stc(float* p, float v)  { *p = v; }
__device__ inline void stc(__bf16* p, float v) { *p = (__bf16)v; }

template <int EPI, typename CT>
__global__ __launch_bounds__(256, 4)
void k_gemm3(const __bf16* __restrict__ A, const __bf16* __restrict__ BT,
             CT* __restrict__ C, int M, int N, int K,
             const float* __restrict__ cosT, const float* __restrict__ sinT,
             const float* __restrict__ qw, const float* __restrict__ kw,
             __bf16* __restrict__ Qr, __bf16* __restrict__ Kr,
             __bf16* __restrict__ Vt) {
  __shared__ alignas(16) __bf16 Al[2][128 * 32];
  __shared__ alignas(16) __bf16 Bl[2][128 * 32];
  const int tid = threadIdx.x;
  const int wid = tid >> 6, lane = tid & 63, g = lane >> 4, r16 = lane & 15;
  const int wm = wid >> 1, wn = wid & 1;
  const int nbm = M >> 7, nbn = N >> 7;
  const int nwg = nbm * nbn;
  int id = blockIdx.x;
  id = (id & 7) * (nwg >> 3) + (id >> 3);   // XCD swizzle (nwg % 8 == 0 here)
  const int bm = id % nbm, bn = id / nbm;

  // staging source: inverse of the row-pair XOR-8 swizzle (see header)
  const int pp = tid >> 3;                  // line index 0..31 (rows 0..63)
  const int c8 = (tid & 7) ^ (pp & 7);
  const int sr1 = 2 * pp + (c8 >> 2);       // 0..63
  const int sr2 = 64 + sr1;                 // 64..127 ((p+32)&7 == p&7)
  const int c1 = (c8 & 3) * 8;
  const __bf16* gA1 = A + (size_t)(bm * 128 + sr1) * K + c1;
  const __bf16* gA2 = A + (size_t)(bm * 128 + sr2) * K + c1;
  const __bf16* gB1 = BT + (size_t)(bn * 128 + sr1) * K + c1;
  const __bf16* gB2 = BT + (size_t)(bn * 128 + sr2) * K + c1;

  // fragment read offsets (row-pair swizzle)
  int aoff[4], boff[4];
#pragma unroll
  for (int m = 0; m < 4; ++m) {
    int row = wm * 64 + m * 16 + r16;
    aoff[m] = (row >> 1) * 64 + (((((row & 1) << 2) | g) ^ ((row >> 1) & 7)) * 8);
  }
#pragma unroll
  for (int n = 0; n < 4; ++n) {
    int row = wn * 64 + n * 16 + r16;
    boff[n] = (row >> 1) * 64 + (((((row & 1) << 2) | g) ^ ((row >> 1) & 7)) * 8);
  }

  auto STAGE = [&](int sl, int kt) {
    const int ko = kt * 32;
    glds16(gA1 + ko, &Al[sl][tid * 8]);
    glds16(gA2 + ko, &Al[sl][2048 + tid * 8]);
    glds16(gB1 + ko, &Bl[sl][tid * 8]);
    glds16(gB2 + ko, &Bl[sl][2048 + tid * 8]);
  };

  f32x4 acc[4][4] = {};
  const int nk = K >> 5;

  STAGE(0, 0);
  for (int kt = 0; kt < nk; ++kt) {
    const int s = kt & 1;
    if (kt + 1 < nk) {
      STAGE(s ^ 1, kt + 1);
      asm volatile("s_waitcnt vmcnt(4)" ::: "memory");
    } else {
      asm volatile("s_waitcnt vmcnt(0)" ::: "memory");
    }
    __builtin_amdgcn_s_barrier();
    bf16x8 af[4], bfr[4];
#pragma unroll
    for (int m = 0; m < 4; ++m) af[m] = *(const bf16x8*)&Al[s][aoff[m]];
#pragma unroll
    for (int n = 0; n < 4; ++n) bfr[n] = *(const bf16x8*)&Bl[s][boff[n]];
    __builtin_amdgcn_s_setprio(1);
#pragma unroll
    for (int m = 0; m < 4; ++m)
#pragma unroll
      for (int n = 0; n < 4; ++n)
        acc[m][n] = mfma16(af[m], bfr[n], acc[m][n]);
    __builtin_amdgcn_s_setprio(0);
    __builtin_amdgcn_s_barrier();   // guard: all reads of slot s done before overwrite
  }

  if (EPI == 0) {
#pragma unroll
    for (int m = 0; m < 4; ++m) {
      int row = bm * 128 + wm * 64 + m * 16 + g * 4;
#pragma unroll
      for (int n = 0; n < 4; ++n) {
        int col = bn * 128 + wn * 64 + n * 16 + r16;
#pragma unroll
        for (int r = 0; r < 4; ++r)
          stc(&C[(size_t)(row + r) * N + col], acc[m][n][r]);
      }
    }
  } else {
    // fused QKV epilogue.  This wave's 64 cols = exactly one head (or V slice).
    const int colbase = bn * 128 + wn * 64;
    const float QSCALE = 0.18033688011112042f;   // 0.125 * log2(e)
    if (colbase < DMODEL + DKV) {
      const bool isq = colbase < DMODEL;
      const float* wp = isq ? qw : kw;
      const float qs = isq ? QSCALE : 1.0f;
      float w4[4];
#pragma unroll
      for (int n = 0; n < 4; ++n) w4[n] = wp[n * 16 + r16];
#pragma unroll
      for (int m = 0; m < 4; ++m) {
        const int rowm = bm * 128 + wm * 64 + m * 16 + g * 4;
        float ss[4];
#pragma unroll
        for (int r = 0; r < 4; ++r) {
          ss[r] = acc[m][0][r] * acc[m][0][r] + acc[m][1][r] * acc[m][1][r] +
                  acc[m][2][r] * acc[m][2][r] + acc[m][3][r] * acc[m][3][r];
#pragma unroll
          for (int mk = 1; mk < 16; mk <<= 1) ss[r] += __shfl_xor(ss[r], mk);
          ss[r] = rsqrtf(ss[r] * (1.0f / HD) + 1e-6f);
        }
#pragma unroll
        for (int r = 0; r < 4; ++r) {
          const int t = rowm + r;
          const int sidx = t & (SEQ - 1);
          const float inv_ = ss[r];
#pragma unroll
          for (int n = 0; n < 4; ++n) {
            const int d = n * 16 + r16;
            const float xn = acc[m][n][r] * inv_ * w4[n];
            const float xp = acc[m][n ^ 2][r] * inv_ * w4[n ^ 2];
            const float rot = (n < 2) ? -xp : xp;
            const float cv = cosT[sidx * HD + d], sv = sinT[sidx * HD + d];
            const float o = (xn * cv + rot * sv) * qs;
            if (isq) {
              const int hq = colbase >> 6;
              Qr[((size_t)t * HH + hq) * HD + d] = (__bf16)o;
            } else {
              const int kvh = (colbase - DMODEL) >> 6;
              Kr[((size_t)t * KVHN + kvh) * HD + d] = (__bf16)o;
            }
          }
        }
      }
    } else {
      const int vc0 = colbase - (DMODEL + DKV);
#pragma unroll
      for (int m = 0; m < 4; ++m) {
        const int rowm = bm * 128 + wm * 64 + m * 16 + g * 4;
#pragma unroll
        for (int n = 0; n < 4; ++n)
#pragma unroll
          for (int r = 0; r < 4; ++r)
            Vt[(size_t)(rowm + r) * DKV + vc0 + n * 16 + r16] = (__bf16)acc[m][n][r];
      }
    }
  }
}

// ---------------- flash attention (causal, GQA) ----------------
// R6-proven geometry (best measured: ~55 us): grid flat 512, block 512
// (8 waves x 16 q-rows; 16 waves/CU at 2 blocks/CU).  EQUAL-WORK BLOCKS:
// sequential complementary pair {15-j, j} (j = f&7) of 128-row q-tiles ->
// 34 kv-iterations for EVERY block (equal wall-iterations AND compute).
// SWAPPED QK^T: sacc = mfma(kf, qf) gives S^T; lane(g,r16) holds
// S[kv=ks*16+g*4+r][q=r16] -> P store is 4x ds_write_b64 into row-major
// P[q][kv]; PV b128 read unchanged.  Denominator: one scalar per lane,
// g-groups summed in epilogue (shfl_xor 16,32) + shfl redistribute.

__global__ __launch_bounds__(512)
void k_attn(const __bf16* __restrict__ Q, const __bf16* __restrict__ Kg,
            const __bf16* __restrict__ VT, __bf16* __restrict__ O) {
  __shared__ alignas(16) __bf16 Kl[2][64 * 64];
  __shared__ alignas(16) __bf16 Vl[2][64 * 64];
  __shared__ alignas(16) __bf16 Pl[8][16 * 72];
  const int f = blockIdx.x;
  const int b = f >> 8;
  const int h = (f & 255) >> 3;
  const int j = f & 7;
  const int kvh = h >> 2;
  const int tid = threadIdx.x, wid = tid >> 6, lane = tid & 63;
  const int g = lane >> 4, r16 = lane & 15;
  __bf16* Pw = Pl[wid];

  const int rr = lane >> 3;                 // row within wave's 8-row slab
  const int cc = (lane & 7) ^ rr;           // swizzled source chunk

  auto STAGE = [&](int buf, int kb) {
    const int krow = kb * 64 + wid * 8 + rr;
    glds16(&Kg[((size_t)(b * SEQ + krow) * KVHN + kvh) * HD + cc * 8],
           &Kl[buf][wid * 512]);
    const int d = wid * 8 + rr;
    glds16(&VT[(size_t)(b * DKV + kvh * HD + d) * SEQ + (size_t)kb * 64 + cc * 8],
           &Vl[buf][wid * 512]);
  };

#pragma unroll 1
  for (int phase = 0; phase < 2; ++phase) {
    const int qt = phase ? j : 15 - j;      // heavy tile first
    const int q0 = qt * 128 + wid * 16;
    const int ntile = 2 * qt + 2;

    bf16x8 qf[2];
#pragma unroll
    for (int h2 = 0; h2 < 2; ++h2)
      qf[h2] = *(const bf16x8*)&Q[(((size_t)b * SEQ + q0 + r16) * HH + h) * HD + h2 * 32 + g * 8];

    f32x4 acc[4] = {};
    float l_q = 0.0f;   // per-lane partial denominator for q = q0 + r16

    STAGE(0, 0);
    asm volatile("s_waitcnt vmcnt(0)" ::: "memory");
    __syncthreads();

    for (int kb = 0; kb < ntile; ++kb) {
      const int cur = kb & 1;
      if (kb + 1 < ntile) STAGE(cur ^ 1, kb + 1);   // prefetch next tile
      const __bf16* Kb = Kl[cur];
      const __bf16* Vb = Vl[cur];
      if (kb * 64 <= q0 + 15) {                     // tile intersects rows
        bf16x8 kf[4][2];
#pragma unroll
        for (int ks = 0; ks < 4; ++ks)
#pragma unroll
          for (int h2 = 0; h2 < 2; ++h2) {
            const int p = r16 + ks * 16;
            const int ch = (g + 4 * h2) ^ (p & 7);
            kf[ks][h2] = *(const bf16x8*)&Kb[p * 64 + ch * 8];
          }
        const bool needmask = (kb * 64 + 63 > q0); // only diagonal tiles mask
        float svv[4][4];
        __builtin_amdgcn_s_setprio(1);
#pragma unroll
        for (int ks = 0; ks < 4; ++ks) {
          f32x4 sacc = {-12.f, -12.f, -12.f, -12.f};   // fixed max in C-init
          sacc = mfma16(kf[ks][0], qf[0], sacc);       // SWAPPED: S^T
          sacc = mfma16(kf[ks][1], qf[1], sacc);
#pragma unroll
          for (int r = 0; r < 4; ++r) svv[ks][r] = sacc[r];
        }
        __builtin_amdgcn_s_setprio(0);
        if (needmask) {
#pragma unroll
          for (int ks = 0; ks < 4; ++ks)
#pragma unroll
            for (int r = 0; r < 4; ++r) {
              int pg = kb * 64 + ks * 16 + g * 4 + r;  // kv (swapped)
              int qg = q0 + r16;                       // q  (swapped)
              if (pg > qg) svv[ks][r] = -1e30f;
            }
        }
        // exp2 + packed b64 store into P[q=r16][kv]: contiguous 4 per ks
#pragma unroll
        for (int ks = 0; ks < 4; ++ks) {
          bf16x4 pk;
#pragma unroll
          for (int r = 0; r < 4; ++r) {
            float p = fast_exp2(svv[ks][r]);
            l_q += p;
            pk[r] = (__bf16)p;
          }
          *(bf16x4*)&Pw[r16 * 72 + ks * 16 + g * 4] = pk;
        }
        bf16x8 pf0 = *(const bf16x8*)&Pw[r16 * 72 + g * 8];
        bf16x8 pf1 = *(const bf16x8*)&Pw[r16 * 72 + 32 + g * 8];
        __builtin_amdgcn_s_setprio(1);
#pragma unroll
        for (int nb = 0; nb < 4; ++nb) {
          const int d = r16 + nb * 16;
          const int ch0 = g ^ (d & 7), ch1 = (4 + g) ^ (d & 7);
          bf16x8 vf0 = *(const bf16x8*)&Vb[d * 64 + ch0 * 8];
          bf16x8 vf1 = *(const bf16x8*)&Vb[d * 64 + ch1 * 8];
          acc[nb] = mfma16(pf0, vf0, acc[nb]);
          acc[nb] = mfma16(pf1, vf1, acc[nb]);
        }
        __builtin_amdgcn_s_setprio(0);
      }
      asm volatile("s_waitcnt vmcnt(0)" ::: "memory");
      __syncthreads();
    }
    // epilogue: complete l over kv (sum the 4 g-groups), redistribute, store
    l_q += __shfl_xor(l_q, 16);
    l_q += __shfl_xor(l_q, 32);
    const float invq = 1.0f / l_q;
    float inv[4];
#pragma unroll
    for (int r = 0; r < 4; ++r) inv[r] = __shfl(invq, g * 4 + r);
#pragma unroll
    for (int nb = 0; nb < 4; ++nb)
#pragma unroll
      for (int r = 0; r < 4; ++r)
        O[(((size_t)b * SEQ + q0 + g * 4 + r) * HH + h) * HD + nb * 16 + r16] =
            (__bf16)(acc[nb][r] * inv[r]);
  }
}

// ---------------- launch ----------------

extern "C" void kernel_launch(void* const* d_in, const int* in_sizes, int n_in,
                              void* d_out, int out_size, void* d_ws, size_t ws_size,
                              hipStream_t stream) {
  const float* hidden = (const float*)d_in[0];
  const float* cosT   = (const float*)d_in[1];
  const float* sinT   = (const float*)d_in[2];
  const float* wq     = (const float*)d_in[3];
  const float* wk     = (const float*)d_in[4];
  const float* wv     = (const float*)d_in[5];
  const float* wo     = (const float*)d_in[6];
  const float* qw     = (const float*)d_in[7];
  const float* kw     = (const float*)d_in[8];
  float* out = (float*)d_out;
  char* ws = (char*)d_ws;

  // workspace layout (64 MB, lifetime-aliased):
  __bf16* Abf  = (__bf16*)(ws);                      // [0,16M) hidden bf16; later Ob
  __bf16* Ob   = Abf;
  __bf16* WT   = (__bf16*)(ws + (16u << 20));        // [16,28M) qkv weights^T
  __bf16* Qr   = (__bf16*)(ws + (28u << 20));        // [28,44M) Q roped (log2 domain)
  __bf16* Kr   = (__bf16*)(ws + (44u << 20));        // [44,48M) K roped
  __bf16* Vtmp = (__bf16*)(ws + (48u << 20));        // [48,52M) V compact [NTOK][512]
  __bf16* VT   = (__bf16*)(ws + (52u << 20));        // [52,56M) V transposed
  __bf16* WoT  = (__bf16*)(ws + (56u << 20));        // [56,64M)

  k_cvt_hidden<<<8192, 256, 0, stream>>>(hidden, Abf);
  k_transpose_w<<<dim3(64, 64), 256, 0, stream>>>(wq, WT, 2048, 2048);
  k_transpose_kv<<<dim3(16, 64, 2), 256, 0, stream>>>(wk, wv, WT);
  k_transpose_w<<<dim3(64, 64), 256, 0, stream>>>(wo, WoT, 2048, 2048);

  k_gemm3<1, __bf16><<<768, 256, 0, stream>>>(Abf, WT, (__bf16*)nullptr,
      NTOK, NQKV, DMODEL, cosT, sinT, qw, kw, Qr, Kr, Vtmp);

  k_transpose_v<<<dim3(16, 64, 2), 256, 0, stream>>>(Vtmp, VT);

  k_attn<<<dim3(512), 512, 0, stream>>>(Qr, Kr, VT, Ob);

  k_gemm3<0, float><<<512, 256, 0, stream>>>(Ob, WoT, out,
      NTOK, DMODEL, DMODEL, nullptr, nullptr, nullptr, nullptr,
      nullptr, nullptr, nullptr);
}

// Round 11
// 186.015 us; speedup vs baseline: 1.2055x; 1.0445x over previous
//
#include <hip/hip_runtime.h>
#include <hip/hip_bf16.h>

#define HH 32
#define KVHN 8
#define HD 64
#define DMODEL 2048
#define SEQ 2048
#define BB 2
#define NTOK 4096     // BB*SEQ
#define DKV 512       // KVHN*HD
#define NQKV 3072     // DMODEL + 2*DKV

typedef __bf16 bf16x8 __attribute__((ext_vector_type(8)));
typedef __bf16 bf16x4 __attribute__((ext_vector_type(4)));
typedef float  f32x4  __attribute__((ext_vector_type(4)));

typedef const __attribute__((address_space(1))) void gvoid_t;
typedef __attribute__((address_space(3))) void lvoid_t;

__device__ inline void glds16(const void* g, void* l) {
  __builtin_amdgcn_global_load_lds((gvoid_t*)g, (lvoid_t*)l, 16, 0, 0);
}

__device__ inline f32x4 mfma16(bf16x8 a, bf16x8 b, f32x4 c) {
  return __builtin_amdgcn_mfma_f32_16x16x32_bf16(a, b, c, 0, 0, 0);
}

// 2^x via v_exp_f32 (glibc shadows __exp2f; this is the HW op directly)
__device__ inline float fast_exp2(float x) {
  float r;
  asm("v_exp_f32 %0, %1" : "=v"(r) : "v"(x));
  return r;
}

// ---------------- merged prep kernel ----------------
// One launch, 18432 blocks of 256 threads, blockIdx-range dispatch:
//   [0, 8192)      hidden f32 -> bf16 (elementwise, 4/thread)
//   [8192, 12288)  wq transpose  -> WT[0..2048)
//   [12288, 14336) wk/wv transpose -> WT[2048..3072)
//   [14336, 18432) wo transpose  -> WoT
// Replaces 4 kernels: fewer launch gaps; BW-bound phases overlap tails.

__global__ __launch_bounds__(256)
void k_prep(const float* __restrict__ hidden, __bf16* __restrict__ Abf,
            const float* __restrict__ wq, const float* __restrict__ wk,
            const float* __restrict__ wv, const float* __restrict__ wo,
            __bf16* __restrict__ WT, __bf16* __restrict__ WoT) {
  __shared__ float tile[32][33];
  const int id = blockIdx.x, tid = threadIdx.x;
  if (id < 8192) {
    int i = (id * 256 + tid) * 4;
    f32x4 v = *(const f32x4*)(hidden + i);
    bf16x4 o;
    o[0] = (__bf16)v[0]; o[1] = (__bf16)v[1];
    o[2] = (__bf16)v[2]; o[3] = (__bf16)v[3];
    *(bf16x4*)(Abf + i) = o;
    return;
  }
  const float* W; __bf16* T; int K, N, n0, k0;
  if (id < 12288) {           // wq
    int t = id - 8192; W = wq; T = WT; K = 2048; N = 2048;
    n0 = (t & 63) * 32; k0 = (t >> 6) * 32;
  } else if (id < 14336) {    // wk (z=0) / wv (z=1)
    int t = id - 12288; int z = t >> 10;
    W = z ? wv : wk; T = WT + (size_t)(2048 + z * 512) * 2048;
    K = 2048; N = 512;
    n0 = (t & 15) * 32; k0 = ((t >> 4) & 63) * 32;
  } else {                    // wo
    int t = id - 14336; W = wo; T = WoT; K = 2048; N = 2048;
    n0 = (t & 63) * 32; k0 = (t >> 6) * 32;
  }
  int tx = tid & 31, ty = tid >> 5;
#pragma unroll
  for (int i = 0; i < 32; i += 8)
    tile[ty + i][tx] = W[(size_t)(k0 + ty + i) * N + n0 + tx];
  __syncthreads();
#pragma unroll
  for (int i = 0; i < 32; i += 8)
    T[(size_t)(n0 + ty + i) * K + k0 + tx] = (__bf16)tile[tx][ty + i];
}

// ---------------- pipelined GEMM: C = A[M][K] * BT[N][K]^T ----------------
// 128x128 tile, BK=32, 4 waves (2M x 2N, 64x64 each), 256 thr, 32KB LDS
// -> 4 blocks/CU co-resident.  Counted-vmcnt prefetch; setprio MFMA.
// LDS layout: ROW-PAIR lines (two 64B rows = one 128B line of 8 chunks,
// slot = c8 ^ (pair&7), c8 = (row&1)*4 + g) -- measured 0 bank conflicts
// (round 10; previous 64B-row XOR-4 layout measured 6.29M/dispatch).
// Staging stays linear in LDS; global source is the inverse permutation.
// EPI==0: plain store to C.  EPI==1: fused QKV epilogue (per-head RMSNorm +
// RoPE, Q pre-scaled by 0.125*log2(e)); V is written DIRECTLY TRANSPOSED
// into VT[b][c][s] (bf16x4 over 4 consecutive tokens = 8B contiguous, g-lanes
// extend to 32B runs) -- eliminates the separate k_transpose_v pass.

__device__ inline void stc(float* p, float v)  { *p = v; }
__device__ inline void stc(__bf16* p, float v) { *p = (__bf16)v; }

template <int EPI, typename CT>
__global__ __launch_bounds__(256, 4)
void k_gemm3(const __bf16* __restrict__ A, const __bf16* __restrict__ BT,
             CT* __restrict__ C, int M, int N, int K,
             const float* __restrict__ cosT, const float* __restrict__ sinT,
             const float* __restrict__ qw, const float* __restrict__ kw,
             __bf16* __restrict__ Qr, __bf16* __restrict__ Kr,
             __bf16* __restrict__ Vt) {
  __shared__ alignas(16) __bf16 Al[2][128 * 32];
  __shared__ alignas(16) __bf16 Bl[2][128 * 32];
  const int tid = threadIdx.x;
  const int wid = tid >> 6, lane = tid & 63, g = lane >> 4, r16 = lane & 15;
  const int wm = wid >> 1, wn = wid & 1;
  const int nbm = M >> 7, nbn = N >> 7;
  const int nwg = nbm * nbn;
  int id = blockIdx.x;
  id = (id & 7) * (nwg >> 3) + (id >> 3);   // XCD swizzle (nwg % 8 == 0 here)
  const int bm = id % nbm, bn = id / nbm;

  // staging source: inverse of the row-pair XOR-8 swizzle (see header)
  const int pp = tid >> 3;                  // line index 0..31 (rows 0..63)
  const int c8 = (tid & 7) ^ (pp & 7);
  const int sr1 = 2 * pp + (c8 >> 2);       // 0..63
  const int sr2 = 64 + sr1;                 // 64..127 ((p+32)&7 == p&7)
  const int c1 = (c8 & 3) * 8;
  const __bf16* gA1 = A + (size_t)(bm * 128 + sr1) * K + c1;
  const __bf16* gA2 = A + (size_t)(bm * 128 + sr2) * K + c1;
  const __bf16* gB1 = BT + (size_t)(bn * 128 + sr1) * K + c1;
  const __bf16* gB2 = BT + (size_t)(bn * 128 + sr2) * K + c1;

  // fragment read offsets (row-pair swizzle)
  int aoff[4], boff[4];
#pragma unroll
  for (int m = 0; m < 4; ++m) {
    int row = wm * 64 + m * 16 + r16;
    aoff[m] = (row >> 1) * 64 + (((((row & 1) << 2) | g) ^ ((row >> 1) & 7)) * 8);
  }
#pragma unroll
  for (int n = 0; n < 4; ++n) {
    int row = wn * 64 + n * 16 + r16;
    boff[n] = (row >> 1) * 64 + (((((row & 1) << 2) | g) ^ ((row >> 1) & 7)) * 8);
  }

  auto STAGE = [&](int sl, int kt) {
    const int ko = kt * 32;
    glds16(gA1 + ko, &Al[sl][tid * 8]);
    glds16(gA2 + ko, &Al[sl][2048 + tid * 8]);
    glds16(gB1 + ko, &Bl[sl][tid * 8]);
    glds16(gB2 + ko, &Bl[sl][2048 + tid * 8]);
  };

  f32x4 acc[4][4] = {};
  const int nk = K >> 5;

  STAGE(0, 0);
  for (int kt = 0; kt < nk; ++kt) {
    const int s = kt & 1;
    if (kt + 1 < nk) {
      STAGE(s ^ 1, kt + 1);
      asm volatile("s_waitcnt vmcnt(4)" ::: "memory");
    } else {
      asm volatile("s_waitcnt vmcnt(0)" ::: "memory");
    }
    __builtin_amdgcn_s_barrier();
    bf16x8 af[4], bfr[4];
#pragma unroll
    for (int m = 0; m < 4; ++m) af[m] = *(const bf16x8*)&Al[s][aoff[m]];
#pragma unroll
    for (int n = 0; n < 4; ++n) bfr[n] = *(const bf16x8*)&Bl[s][boff[n]];
    __builtin_amdgcn_s_setprio(1);
#pragma unroll
    for (int m = 0; m < 4; ++m)
#pragma unroll
      for (int n = 0; n < 4; ++n)
        acc[m][n] = mfma16(af[m], bfr[n], acc[m][n]);
    __builtin_amdgcn_s_setprio(0);
    __builtin_amdgcn_s_barrier();   // guard: all reads of slot s done before overwrite
  }

  if (EPI == 0) {
#pragma unroll
    for (int m = 0; m < 4; ++m) {
      int row = bm * 128 + wm * 64 + m * 16 + g * 4;
#pragma unroll
      for (int n = 0; n < 4; ++n) {
        int col = bn * 128 + wn * 64 + n * 16 + r16;
#pragma unroll
        for (int r = 0; r < 4; ++r)
          stc(&C[(size_t)(row + r) * N + col], acc[m][n][r]);
      }
    }
  } else {
    // fused QKV epilogue.  This wave's 64 cols = exactly one head (or V slice).
    const int colbase = bn * 128 + wn * 64;
    const float QSCALE = 0.18033688011112042f;   // 0.125 * log2(e)
    if (colbase < DMODEL + DKV) {
      const bool isq = colbase < DMODEL;
      const float* wp = isq ? qw : kw;
      const float qs = isq ? QSCALE : 1.0f;
      float w4[4];
#pragma unroll
      for (int n = 0; n < 4; ++n) w4[n] = wp[n * 16 + r16];
#pragma unroll
      for (int m = 0; m < 4; ++m) {
        const int rowm = bm * 128 + wm * 64 + m * 16 + g * 4;
        float ss[4];
#pragma unroll
        for (int r = 0; r < 4; ++r) {
          ss[r] = acc[m][0][r] * acc[m][0][r] + acc[m][1][r] * acc[m][1][r] +
                  acc[m][2][r] * acc[m][2][r] + acc[m][3][r] * acc[m][3][r];
#pragma unroll
          for (int mk = 1; mk < 16; mk <<= 1) ss[r] += __shfl_xor(ss[r], mk);
          ss[r] = rsqrtf(ss[r] * (1.0f / HD) + 1e-6f);
        }
#pragma unroll
        for (int r = 0; r < 4; ++r) {
          const int t = rowm + r;
          const int sidx = t & (SEQ - 1);
          const float inv_ = ss[r];
#pragma unroll
          for (int n = 0; n < 4; ++n) {
            const int d = n * 16 + r16;
            const float xn = acc[m][n][r] * inv_ * w4[n];
            const float xp = acc[m][n ^ 2][r] * inv_ * w4[n ^ 2];
            const float rot = (n < 2) ? -xp : xp;
            const float cv = cosT[sidx * HD + d], sv = sinT[sidx * HD + d];
            const float o = (xn * cv + rot * sv) * qs;
            if (isq) {
              const int hq = colbase >> 6;
              Qr[((size_t)t * HH + hq) * HD + d] = (__bf16)o;
            } else {
              const int kvh = (colbase - DMODEL) >> 6;
              Kr[((size_t)t * KVHN + kvh) * HD + d] = (__bf16)o;
            }
          }
        }
      }
    } else {
      // V: write directly TRANSPOSED into VT[b][c][s].  The 4 r-values are
      // 4 consecutive tokens (s-contiguous) -> one bf16x4 (8B) store; the
      // 4 g-lanes extend each channel to a 32B contiguous run.
      const int vc0 = colbase - (DMODEL + DKV);
#pragma unroll
      for (int m = 0; m < 4; ++m) {
        const int rowm = bm * 128 + wm * 64 + m * 16 + g * 4;
        const int bb2 = rowm >> 11;          // batch (SEQ = 2048)
        const int s0 = rowm & (SEQ - 1);     // 4-aligned, same batch for r=0..3
#pragma unroll
        for (int n = 0; n < 4; ++n) {
          const int c = vc0 + n * 16 + r16;
          bf16x4 pk;
#pragma unroll
          for (int r = 0; r < 4; ++r) pk[r] = (__bf16)acc[m][n][r];
          *(bf16x4*)&Vt[((size_t)bb2 * DKV + c) * SEQ + s0] = pk;
        }
      }
    }
  }
}

// ---------------- flash attention (causal, GQA) ----------------
// R6-proven geometry (best measured): grid flat 512, block 512
// (8 waves x 16 q-rows; 16 waves/CU at 2 blocks/CU).  EQUAL-WORK BLOCKS:
// sequential complementary pair {15-j, j} (j = f&7) of 128-row q-tiles ->
// 34 kv-iterations for EVERY block (equal wall-iterations AND compute).
// SWAPPED QK^T: sacc = mfma(kf, qf) gives S^T; lane(g,r16) holds
// S[kv=ks*16+g*4+r][q=r16] -> P store is 4x ds_write_b64 into row-major
// P[q][kv]; PV b128 read unchanged.  Denominator: one scalar per lane,
// g-groups summed in epilogue (shfl_xor 16,32) + shfl redistribute.

__global__ __launch_bounds__(512)
void k_attn(const __bf16* __restrict__ Q, const __bf16* __restrict__ Kg,
            const __bf16* __restrict__ VT, __bf16* __restrict__ O) {
  __shared__ alignas(16) __bf16 Kl[2][64 * 64];
  __shared__ alignas(16) __bf16 Vl[2][64 * 64];
  __shared__ alignas(16) __bf16 Pl[8][16 * 72];
  const int f = blockIdx.x;
  const int b = f >> 8;
  const int h = (f & 255) >> 3;
  const int j = f & 7;
  const int kvh = h >> 2;
  const int tid = threadIdx.x, wid = tid >> 6, lane = tid & 63;
  const int g = lane >> 4, r16 = lane & 15;
  __bf16* Pw = Pl[wid];

  const int rr = lane >> 3;                 // row within wave's 8-row slab
  const int cc = (lane & 7) ^ rr;           // swizzled source chunk

  auto STAGE = [&](int buf, int kb) {
    const int krow = kb * 64 + wid * 8 + rr;
    glds16(&Kg[((size_t)(b * SEQ + krow) * KVHN + kvh) * HD + cc * 8],
           &Kl[buf][wid * 512]);
    const int d = wid * 8 + rr;
    glds16(&VT[(size_t)(b * DKV + kvh * HD + d) * SEQ + (size_t)kb * 64 + cc * 8],
           &Vl[buf][wid * 512]);
  };

#pragma unroll 1
  for (int phase = 0; phase < 2; ++phase) {
    const int qt = phase ? j : 15 - j;      // heavy tile first
    const int q0 = qt * 128 + wid * 16;
    const int ntile = 2 * qt + 2;

    bf16x8 qf[2];
#pragma unroll
    for (int h2 = 0; h2 < 2; ++h2)
      qf[h2] = *(const bf16x8*)&Q[(((size_t)b * SEQ + q0 + r16) * HH + h) * HD + h2 * 32 + g * 8];

    f32x4 acc[4] = {};
    float l_q = 0.0f;   // per-lane partial denominator for q = q0 + r16

    STAGE(0, 0);
    asm volatile("s_waitcnt vmcnt(0)" ::: "memory");
    __syncthreads();

    for (int kb = 0; kb < ntile; ++kb) {
      const int cur = kb & 1;
      if (kb + 1 < ntile) STAGE(cur ^ 1, kb + 1);   // prefetch next tile
      const __bf16* Kb = Kl[cur];
      const __bf16* Vb = Vl[cur];
      if (kb * 64 <= q0 + 15) {                     // tile intersects rows
        bf16x8 kf[4][2];
#pragma unroll
        for (int ks = 0; ks < 4; ++ks)
#pragma unroll
          for (int h2 = 0; h2 < 2; ++h2) {
            const int p = r16 + ks * 16;
            const int ch = (g + 4 * h2) ^ (p & 7);
            kf[ks][h2] = *(const bf16x8*)&Kb[p * 64 + ch * 8];
          }
        const bool needmask = (kb * 64 + 63 > q0); // only diagonal tiles mask
        float svv[4][4];
        __builtin_amdgcn_s_setprio(1);
#pragma unroll
        for (int ks = 0; ks < 4; ++ks) {
          f32x4 sacc = {-12.f, -12.f, -12.f, -12.f};   // fixed max in C-init
          sacc = mfma16(kf[ks][0], qf[0], sacc);       // SWAPPED: S^T
          sacc = mfma16(kf[ks][1], qf[1], sacc);
#pragma unroll
          for (int r = 0; r < 4; ++r) svv[ks][r] = sacc[r];
        }
        __builtin_amdgcn_s_setprio(0);
        if (needmask) {
#pragma unroll
          for (int ks = 0; ks < 4; ++ks)
#pragma unroll
            for (int r = 0; r < 4; ++r) {
              int pg = kb * 64 + ks * 16 + g * 4 + r;  // kv (swapped)
              int qg = q0 + r16;                       // q  (swapped)
              if (pg > qg) svv[ks][r] = -1e30f;
            }
        }
        // exp2 + packed b64 store into P[q=r16][kv]: contiguous 4 per ks
#pragma unroll
        for (int ks = 0; ks < 4; ++ks) {
          bf16x4 pk;
#pragma unroll
          for (int r = 0; r < 4; ++r) {
            float p = fast_exp2(svv[ks][r]);
            l_q += p;
            pk[r] = (__bf16)p;
          }
          *(bf16x4*)&Pw[r16 * 72 + ks * 16 + g * 4] = pk;
        }
        bf16x8 pf0 = *(const bf16x8*)&Pw[r16 * 72 + g * 8];
        bf16x8 pf1 = *(const bf16x8*)&Pw[r16 * 72 + 32 + g * 8];
        __builtin_amdgcn_s_setprio(1);
#pragma unroll
        for (int nb = 0; nb < 4; ++nb) {
          const int d = r16 + nb * 16;
          const int ch0 = g ^ (d & 7), ch1 = (4 + g) ^ (d & 7);
          bf16x8 vf0 = *(const bf16x8*)&Vb[d * 64 + ch0 * 8];
          bf16x8 vf1 = *(const bf16x8*)&Vb[d * 64 + ch1 * 8];
          acc[nb] = mfma16(pf0, vf0, acc[nb]);
          acc[nb] = mfma16(pf1, vf1, acc[nb]);
        }
        __builtin_amdgcn_s_setprio(0);
      }
      asm volatile("s_waitcnt vmcnt(0)" ::: "memory");
      __syncthreads();
    }
    // epilogue: complete l over kv (sum the 4 g-groups), redistribute, store
    l_q += __shfl_xor(l_q, 16);
    l_q += __shfl_xor(l_q, 32);
    const float invq = 1.0f / l_q;
    float inv[4];
#pragma unroll
    for (int r = 0; r < 4; ++r) inv[r] = __shfl(invq, g * 4 + r);
#pragma unroll
    for (int nb = 0; nb < 4; ++nb)
#pragma unroll
      for (int r = 0; r < 4; ++r)
        O[(((size_t)b * SEQ + q0 + g * 4 + r) * HH + h) * HD + nb * 16 + r16] =
            (__bf16)(acc[nb][r] * inv[r]);
  }
}

// ---------------- launch ----------------

extern "C" void kernel_launch(void* const* d_in, const int* in_sizes, int n_in,
                              void* d_out, int out_size, void* d_ws, size_t ws_size,
                              hipStream_t stream) {
  const float* hidden = (const float*)d_in[0];
  const float* cosT   = (const float*)d_in[1];
  const float* sinT   = (const float*)d_in[2];
  const float* wq     = (const float*)d_in[3];
  const float* wk     = (const float*)d_in[4];
  const float* wv     = (const float*)d_in[5];
  const float* wo     = (const float*)d_in[6];
  const float* qw     = (const float*)d_in[7];
  const float* kw     = (const float*)d_in[8];
  float* out = (float*)d_out;
  char* ws = (char*)d_ws;

  // workspace layout (64 MB, lifetime-aliased):
  __bf16* Abf  = (__bf16*)(ws);                      // [0,16M) hidden bf16; later Ob
  __bf16* Ob   = Abf;
  __bf16* WT   = (__bf16*)(ws + (16u << 20));        // [16,28M) qkv weights^T
  __bf16* Qr   = (__bf16*)(ws + (28u << 20));        // [28,44M) Q roped (log2 domain)
  __bf16* Kr   = (__bf16*)(ws + (44u << 20));        // [44,48M) K roped
  __bf16* VT   = (__bf16*)(ws + (52u << 20));        // [52,56M) V transposed (direct)
  __bf16* WoT  = (__bf16*)(ws + (56u << 20));        // [56,64M)

  k_prep<<<18432, 256, 0, stream>>>(hidden, Abf, wq, wk, wv, wo, WT, WoT);

  k_gemm3<1, __bf16><<<768, 256, 0, stream>>>(Abf, WT, (__bf16*)nullptr,
      NTOK, NQKV, DMODEL, cosT, sinT, qw, kw, Qr, Kr, VT);

  k_attn<<<dim3(512), 512, 0, stream>>>(Qr, Kr, VT, Ob);

  k_gemm3<0, float><<<512, 256, 0, stream>>>(Ob, WoT, out,
      NTOK, DMODEL, DMODEL, nullptr, nullptr, nullptr, nullptr,
      nullptr, nullptr, nullptr);
}

// Round 12
// 185.064 us; speedup vs baseline: 1.2116x; 1.0051x over previous
//
#include <hip/hip_runtime.h>
#include <hip/hip_bf16.h>

#define HH 32
#define KVHN 8
#define HD 64
#define DMODEL 2048
#define SEQ 2048
#define BB 2
#define NTOK 4096     // BB*SEQ
#define DKV 512       // KVHN*HD
#define NQKV 3072     // DMODEL + 2*DKV

typedef __bf16 bf16x8 __attribute__((ext_vector_type(8)));
typedef __bf16 bf16x4 __attribute__((ext_vector_type(4)));
typedef float  f32x4  __attribute__((ext_vector_type(4)));

typedef const __attribute__((address_space(1))) void gvoid_t;
typedef __attribute__((address_space(3))) void lvoid_t;

__device__ inline void glds16(const void* g, void* l) {
  __builtin_amdgcn_global_load_lds((gvoid_t*)g, (lvoid_t*)l, 16, 0, 0);
}

__device__ inline f32x4 mfma16(bf16x8 a, bf16x8 b, f32x4 c) {
  return __builtin_amdgcn_mfma_f32_16x16x32_bf16(a, b, c, 0, 0, 0);
}

// 2^x via v_exp_f32 (glibc shadows __exp2f; this is the HW op directly)
__device__ inline float fast_exp2(float x) {
  float r;
  asm("v_exp_f32 %0, %1" : "=v"(r) : "v"(x));
  return r;
}

// ---------------- merged prep kernel ----------------
// One launch, 18432 blocks of 256 threads, blockIdx-range dispatch:
//   [0, 8192)      hidden f32 -> bf16 (elementwise, 4/thread)
//   [8192, 12288)  wq transpose  -> WT[0..2048)
//   [12288, 14336) wk/wv transpose -> WT[2048..3072)
//   [14336, 18432) wo transpose  -> WoT

__global__ __launch_bounds__(256)
void k_prep(const float* __restrict__ hidden, __bf16* __restrict__ Abf,
            const float* __restrict__ wq, const float* __restrict__ wk,
            const float* __restrict__ wv, const float* __restrict__ wo,
            __bf16* __restrict__ WT, __bf16* __restrict__ WoT) {
  __shared__ float tile[32][33];
  const int id = blockIdx.x, tid = threadIdx.x;
  if (id < 8192) {
    int i = (id * 256 + tid) * 4;
    f32x4 v = *(const f32x4*)(hidden + i);
    bf16x4 o;
    o[0] = (__bf16)v[0]; o[1] = (__bf16)v[1];
    o[2] = (__bf16)v[2]; o[3] = (__bf16)v[3];
    *(bf16x4*)(Abf + i) = o;
    return;
  }
  const float* W; __bf16* T; int K, N, n0, k0;
  if (id < 12288) {           // wq
    int t = id - 8192; W = wq; T = WT; K = 2048; N = 2048;
    n0 = (t & 63) * 32; k0 = (t >> 6) * 32;
  } else if (id < 14336) {    // wk (z=0) / wv (z=1)
    int t = id - 12288; int z = t >> 10;
    W = z ? wv : wk; T = WT + (size_t)(2048 + z * 512) * 2048;
    K = 2048; N = 512;
    n0 = (t & 15) * 32; k0 = ((t >> 4) & 63) * 32;
  } else {                    // wo
    int t = id - 14336; W = wo; T = WoT; K = 2048; N = 2048;
    n0 = (t & 63) * 32; k0 = (t >> 6) * 32;
  }
  int tx = tid & 31, ty = tid >> 5;
#pragma unroll
  for (int i = 0; i < 32; i += 8)
    tile[ty + i][tx] = W[(size_t)(k0 + ty + i) * N + n0 + tx];
  __syncthreads();
#pragma unroll
  for (int i = 0; i < 32; i += 8)
    T[(size_t)(n0 + ty + i) * K + k0 + tx] = (__bf16)tile[tx][ty + i];
}

// ---------------- 2-phase GEMM (WO): C = A * BT^T ----------------
// 128x128 tile, BK=32, 4 waves, 32KB LDS, row-pair XOR-8 LDS layout
// (0 bank conflicts measured, round 10), counted-vmcnt prefetch.

__device__ inline void stc(float* p, float v)  { *p = v; }
__device__ inline void stc(__bf16* p, float v) { *p = (__bf16)v; }

template <int EPI, typename CT>
__global__ __launch_bounds__(256, 4)
void k_gemm3(const __bf16* __restrict__ A, const __bf16* __restrict__ BT,
             CT* __restrict__ C, int M, int N, int K) {
  __shared__ alignas(16) __bf16 Al[2][128 * 32];
  __shared__ alignas(16) __bf16 Bl[2][128 * 32];
  const int tid = threadIdx.x;
  const int wid = tid >> 6, lane = tid & 63, g = lane >> 4, r16 = lane & 15;
  const int wm = wid >> 1, wn = wid & 1;
  const int nbm = M >> 7, nbn = N >> 7;
  const int nwg = nbm * nbn;
  int id = blockIdx.x;
  id = (id & 7) * (nwg >> 3) + (id >> 3);   // XCD swizzle (nwg % 8 == 0 here)
  const int bm = id % nbm, bn = id / nbm;

  const int pp = tid >> 3;
  const int c8 = (tid & 7) ^ (pp & 7);
  const int sr1 = 2 * pp + (c8 >> 2);
  const int sr2 = 64 + sr1;
  const int c1 = (c8 & 3) * 8;
  const __bf16* gA1 = A + (size_t)(bm * 128 + sr1) * K + c1;
  const __bf16* gA2 = A + (size_t)(bm * 128 + sr2) * K + c1;
  const __bf16* gB1 = BT + (size_t)(bn * 128 + sr1) * K + c1;
  const __bf16* gB2 = BT + (size_t)(bn * 128 + sr2) * K + c1;

  int aoff[4], boff[4];
#pragma unroll
  for (int m = 0; m < 4; ++m) {
    int row = wm * 64 + m * 16 + r16;
    aoff[m] = (row >> 1) * 64 + (((((row & 1) << 2) | g) ^ ((row >> 1) & 7)) * 8);
  }
#pragma unroll
  for (int n = 0; n < 4; ++n) {
    int row = wn * 64 + n * 16 + r16;
    boff[n] = (row >> 1) * 64 + (((((row & 1) << 2) | g) ^ ((row >> 1) & 7)) * 8);
  }

  auto STAGE = [&](int sl, int kt) {
    const int ko = kt * 32;
    glds16(gA1 + ko, &Al[sl][tid * 8]);
    glds16(gA2 + ko, &Al[sl][2048 + tid * 8]);
    glds16(gB1 + ko, &Bl[sl][tid * 8]);
    glds16(gB2 + ko, &Bl[sl][2048 + tid * 8]);
  };

  f32x4 acc[4][4] = {};
  const int nk = K >> 5;

  STAGE(0, 0);
  for (int kt = 0; kt < nk; ++kt) {
    const int s = kt & 1;
    if (kt + 1 < nk) {
      STAGE(s ^ 1, kt + 1);
      asm volatile("s_waitcnt vmcnt(4)" ::: "memory");
    } else {
      asm volatile("s_waitcnt vmcnt(0)" ::: "memory");
    }
    __builtin_amdgcn_s_barrier();
    bf16x8 af[4], bfr[4];
#pragma unroll
    for (int m = 0; m < 4; ++m) af[m] = *(const bf16x8*)&Al[s][aoff[m]];
#pragma unroll
    for (int n = 0; n < 4; ++n) bfr[n] = *(const bf16x8*)&Bl[s][boff[n]];
    __builtin_amdgcn_s_setprio(1);
#pragma unroll
    for (int m = 0; m < 4; ++m)
#pragma unroll
      for (int n = 0; n < 4; ++n)
        acc[m][n] = mfma16(af[m], bfr[n], acc[m][n]);
    __builtin_amdgcn_s_setprio(0);
    __builtin_amdgcn_s_barrier();
  }

#pragma unroll
  for (int m = 0; m < 4; ++m) {
    int row = bm * 128 + wm * 64 + m * 16 + g * 4;
#pragma unroll
    for (int n = 0; n < 4; ++n) {
      int col = bn * 128 + wn * 64 + n * 16 + r16;
#pragma unroll
      for (int r = 0; r < 4; ++r)
        stc(&C[(size_t)(row + r) * N + col], acc[m][n][r]);
    }
  }
}

// ---------------- 8-phase 256^2 GEMM with fused QKV epilogue ----------------
// BM=BN=256, BK=64, 512 thr (8 waves, 2M x 4N, 128x64/wave), 128KB LDS as
// 4 single-K-tile buffers: AlE/AlO (even/odd K-tile A), BlE/BlO (B).
// Iteration i covers tiles t=2i (phases 0-3, E-bufs) and t+1 (4-7, O-bufs).
// Per phase: {4 A ds_read_b128 (+8 B at mp==0) -> 1 half-tile stage (2 glds)
// -> [vmcnt at p3/p7] -> barrier -> lgkmcnt(0) -> setprio(1) -> 16 MFMA
// (m-pair quadrant) -> setprio(0) -> barrier}.
// Staging ledger (target dead >=2 barriers before issue; verified by region
// lifetime analysis): p0/p1: A(t+1)->AlO (AlO's A(t-1) reads done prev p7);
// p2/p3: B(t+2)->BlE (B(t) reads done p0); p4/p5: A(t+2)->AlE (A(t) reads
// done p3); p6/p7: B(t+3)->BlO (B(t+1) reads done p4).
// Counted vmcnt(4) at p3 and p7 ONLY: per-thread outstanding at p3 = 12
// (B(t+1) 4 + A(t+1) 4 + B(t+2) 4) -> retire oldest 8 = exactly what p4
// needs; symmetric at p7.  Epilogue drains with vmcnt(0) when stages guard
// off.  Staging/fragment swizzle + fused RMSNorm/RoPE epilogue are the
// round-4-correctness-verified versions (XOR-8 chunk, 0 bank conflicts).

template <int EPI, typename CT>
__global__ __launch_bounds__(512, 2)
void k_gemm8(const __bf16* __restrict__ A, const __bf16* __restrict__ BT,
             CT* __restrict__ C, int M, int N, int K,
             const float* __restrict__ cosT, const float* __restrict__ sinT,
             const float* __restrict__ qw, const float* __restrict__ kw,
             __bf16* __restrict__ Qr, __bf16* __restrict__ Kr,
             __bf16* __restrict__ Vt) {
  __shared__ alignas(16) __bf16 AlE[256 * 64];
  __shared__ alignas(16) __bf16 AlO[256 * 64];
  __shared__ alignas(16) __bf16 BlE[256 * 64];
  __shared__ alignas(16) __bf16 BlO[256 * 64];
  const int tid = threadIdx.x;
  const int wid = tid >> 6, lane = tid & 63, g = lane >> 4, r16 = lane & 15;
  const int wm = wid >> 2, wn = wid & 3;          // 2M x 4N
  const int nbm = M >> 8, nbn = N >> 8;
  const int nwg = nbm * nbn;
  int id = blockIdx.x;
  id = (id & 7) * (nwg >> 3) + (id >> 3);         // XCD swizzle (nwg % 8 == 0)
  const int bm = id % nbm, bn = id / nbm;

  // staging: 512 thr x 16B = 64 rows/round; XOR-8 pre-swizzled source
  const int srow = tid >> 3;                      // 0..63
  const int schunk = tid & 7;
  const int sc = (schunk ^ (srow & 7)) * 8;
  const __bf16* gA = A + (size_t)(bm * 256 + srow) * K + sc;
  const __bf16* gB = BT + (size_t)(bn * 256 + srow) * K + sc;

  auto SA = [&](__bf16* buf, int kt, int q) {     // rows q*64 .. q*64+63
    glds16(gA + (size_t)q * 64 * K + kt * 64,
           &buf[(q * 64 + srow) * 64 + schunk * 8]);
  };
  auto SB = [&](__bf16* buf, int kt, int q) {
    glds16(gB + (size_t)q * 64 * K + kt * 64,
           &buf[(q * 64 + srow) * 64 + schunk * 8]);
  };

  const int cs0 = (g ^ (r16 & 7)) * 8;
  const int cs1 = ((4 + g) ^ (r16 & 7)) * 8;

  f32x4 acc[8][4] = {};
  const int nk = K >> 6;                          // BK=64; nk even

  // prologue: A(0)->AlE, B(0)->BlE, B(1)->BlO; keep B(1) in flight
  SA(AlE, 0, 0); SA(AlE, 0, 1); SA(AlE, 0, 2); SA(AlE, 0, 3);
  SB(BlE, 0, 0); SB(BlE, 0, 1); SB(BlE, 0, 2); SB(BlE, 0, 3);
  SB(BlO, 1, 0); SB(BlO, 1, 1); SB(BlO, 1, 2); SB(BlO, 1, 3);
  asm volatile("s_waitcnt vmcnt(4)" ::: "memory");
  __builtin_amdgcn_s_barrier();

#pragma unroll 1
  for (int i = 0; i < (nk >> 1); ++i) {
    const int t = 2 * i;
    const bool s2 = (t + 2 < nk), s3 = (t + 3 < nk);
    bf16x8 bfr[4][2];
#pragma unroll
    for (int p = 0; p < 8; ++p) {
      const __bf16* Ab = (p < 4) ? AlE : AlO;
      const __bf16* Bb = (p < 4) ? BlE : BlO;
      const int mp = p & 3;
      bf16x8 af[2][2];
#pragma unroll
      for (int j = 0; j < 2; ++j) {
        const int row = wm * 128 + (2 * mp + j) * 16 + r16;
        af[j][0] = *(const bf16x8*)&Ab[row * 64 + cs0];
        af[j][1] = *(const bf16x8*)&Ab[row * 64 + cs1];
      }
      if (mp == 0) {
#pragma unroll
        for (int n = 0; n < 4; ++n) {
          const int row = wn * 64 + n * 16 + r16;
          bfr[n][0] = *(const bf16x8*)&Bb[row * 64 + cs0];
          bfr[n][1] = *(const bf16x8*)&Bb[row * 64 + cs1];
        }
      }
      asm volatile("" ::: "memory");              // pin reads before stages
      switch (p) {
        case 0: SA(AlO, t + 1, 0); SA(AlO, t + 1, 1); break;
        case 1: SA(AlO, t + 1, 2); SA(AlO, t + 1, 3); break;
        case 2: if (s2) { SB(BlE, t + 2, 0); SB(BlE, t + 2, 1); } break;
        case 3: if (s2) { SB(BlE, t + 2, 2); SB(BlE, t + 2, 3); } break;
        case 4: if (s2) { SA(AlE, t + 2, 0); SA(AlE, t + 2, 1); } break;
        case 5: if (s2) { SA(AlE, t + 2, 2); SA(AlE, t + 2, 3); } break;
        case 6: if (s3) { SB(BlO, t + 3, 0); SB(BlO, t + 3, 1); } break;
        case 7: if (s3) { SB(BlO, t + 3, 2); SB(BlO, t + 3, 3); } break;
      }
      if (p == 3) {
        if (s2) asm volatile("s_waitcnt vmcnt(4)" ::: "memory");
        else    asm volatile("s_waitcnt vmcnt(0)" ::: "memory");
      }
      if (p == 7) {
        if (s3) asm volatile("s_waitcnt vmcnt(4)" ::: "memory");
        else    asm volatile("s_waitcnt vmcnt(0)" ::: "memory");
      }
      __builtin_amdgcn_s_barrier();
      asm volatile("s_waitcnt lgkmcnt(0)" ::: "memory");
      __builtin_amdgcn_s_setprio(1);
#pragma unroll
      for (int j = 0; j < 2; ++j)
#pragma unroll
        for (int n = 0; n < 4; ++n) {
          acc[2 * mp + j][n] = mfma16(af[j][0], bfr[n][0], acc[2 * mp + j][n]);
          acc[2 * mp + j][n] = mfma16(af[j][1], bfr[n][1], acc[2 * mp + j][n]);
        }
      __builtin_amdgcn_s_setprio(0);
      __builtin_amdgcn_s_barrier();
    }
  }

  if (EPI == 0) {
#pragma unroll
    for (int m = 0; m < 8; ++m) {
      int row = bm * 256 + wm * 128 + m * 16 + g * 4;
#pragma unroll
      for (int n = 0; n < 4; ++n) {
        int col = bn * 256 + wn * 64 + n * 16 + r16;
#pragma unroll
        for (int r = 0; r < 4; ++r)
          stc(&C[(size_t)(row + r) * N + col], acc[m][n][r]);
      }
    }
  } else {
    // fused QKV epilogue: this wave's 64 cols = exactly one head (or V slice)
    const int colbase = bn * 256 + wn * 64;
    const float QSCALE = 0.18033688011112042f;    // 0.125 * log2(e)
    if (colbase < DMODEL + DKV) {
      const bool isq = colbase < DMODEL;
      const float* wp = isq ? qw : kw;
      const float qs = isq ? QSCALE : 1.0f;
      float w4[4];
#pragma unroll
      for (int n = 0; n < 4; ++n) w4[n] = wp[n * 16 + r16];
#pragma unroll
      for (int m = 0; m < 8; ++m) {
        const int rowm = bm * 256 + wm * 128 + m * 16 + g * 4;
        float ss[4];
#pragma unroll
        for (int r = 0; r < 4; ++r) {
          ss[r] = acc[m][0][r] * acc[m][0][r] + acc[m][1][r] * acc[m][1][r] +
                  acc[m][2][r] * acc[m][2][r] + acc[m][3][r] * acc[m][3][r];
#pragma unroll
          for (int mk = 1; mk < 16; mk <<= 1) ss[r] += __shfl_xor(ss[r], mk);
          ss[r] = rsqrtf(ss[r] * (1.0f / HD) + 1e-6f);
        }
#pragma unroll
        for (int r = 0; r < 4; ++r) {
          const int t = rowm + r;
          const int sidx = t & (SEQ - 1);
          const float inv_ = ss[r];
#pragma unroll
          for (int n = 0; n < 4; ++n) {
            const int d = n * 16 + r16;
            const float xn = acc[m][n][r] * inv_ * w4[n];
            const float xp = acc[m][n ^ 2][r] * inv_ * w4[n ^ 2];
            const float rot = (n < 2) ? -xp : xp;
            const float cv = cosT[sidx * HD + d], sv = sinT[sidx * HD + d];
            const float o = (xn * cv + rot * sv) * qs;
            if (isq) {
              const int hq = colbase >> 6;
              Qr[((size_t)t * HH + hq) * HD + d] = (__bf16)o;
            } else {
              const int kvh = (colbase - DMODEL) >> 6;
              Kr[((size_t)t * KVHN + kvh) * HD + d] = (__bf16)o;
            }
          }
        }
      }
    } else {
      // V: write directly TRANSPOSED into VT[b][c][s]
      const int vc0 = colbase - (DMODEL + DKV);
#pragma unroll
      for (int m = 0; m < 8; ++m) {
        const int rowm = bm * 256 + wm * 128 + m * 16 + g * 4;
        const int bb2 = rowm >> 11;          // batch (SEQ = 2048)
        const int s0 = rowm & (SEQ - 1);
#pragma unroll
        for (int n = 0; n < 4; ++n) {
          const int c = vc0 + n * 16 + r16;
          bf16x4 pk;
#pragma unroll
          for (int r = 0; r < 4; ++r) pk[r] = (__bf16)acc[m][n][r];
          *(bf16x4*)&Vt[((size_t)bb2 * DKV + c) * SEQ + s0] = pk;
        }
      }
    }
  }
}

// ---------------- flash attention (causal, GQA) ----------------
// R6-proven geometry: grid flat 512, block 512 (8 waves x 16 q-rows;
// 16 waves/CU at 2 blocks/CU).  EQUAL-WORK BLOCKS: sequential complementary
// pair {15-j, j} (j = f&7) of 128-row q-tiles -> 34 kv-iterations for EVERY
// block.  SWAPPED QK^T: sacc = mfma(kf, qf) gives S^T; P store is 4x
// ds_write_b64 into row-major P[q][kv]; PV b128 read unchanged.

__global__ __launch_bounds__(512)
void k_attn(const __bf16* __restrict__ Q, const __bf16* __restrict__ Kg,
            const __bf16* __restrict__ VT, __bf16* __restrict__ O) {
  __shared__ alignas(16) __bf16 Kl[2][64 * 64];
  __shared__ alignas(16) __bf16 Vl[2][64 * 64];
  __shared__ alignas(16) __bf16 Pl[8][16 * 72];
  const int f = blockIdx.x;
  const int b = f >> 8;
  const int h = (f & 255) >> 3;
  const int j = f & 7;
  const int kvh = h >> 2;
  const int tid = threadIdx.x, wid = tid >> 6, lane = tid & 63;
  const int g = lane >> 4, r16 = lane & 15;
  __bf16* Pw = Pl[wid];

  const int rr = lane >> 3;                 // row within wave's 8-row slab
  const int cc = (lane & 7) ^ rr;           // swizzled source chunk

  auto STAGE = [&](int buf, int kb) {
    const int krow = kb * 64 + wid * 8 + rr;
    glds16(&Kg[((size_t)(b * SEQ + krow) * KVHN + kvh) * HD + cc * 8],
           &Kl[buf][wid * 512]);
    const int d = wid * 8 + rr;
    glds16(&VT[(size_t)(b * DKV + kvh * HD + d) * SEQ + (size_t)kb * 64 + cc * 8],
           &Vl[buf][wid * 512]);
  };

#pragma unroll 1
  for (int phase = 0; phase < 2; ++phase) {
    const int qt = phase ? j : 15 - j;      // heavy tile first
    const int q0 = qt * 128 + wid * 16;
    const int ntile = 2 * qt + 2;

    bf16x8 qf[2];
#pragma unroll
    for (int h2 = 0; h2 < 2; ++h2)
      qf[h2] = *(const bf16x8*)&Q[(((size_t)b * SEQ + q0 + r16) * HH + h) * HD + h2 * 32 + g * 8];

    f32x4 acc[4] = {};
    float l_q = 0.0f;   // per-lane partial denominator for q = q0 + r16

    STAGE(0, 0);
    asm volatile("s_waitcnt vmcnt(0)" ::: "memory");
    __syncthreads();

    for (int kb = 0; kb < ntile; ++kb) {
      const int cur = kb & 1;
      if (kb + 1 < ntile) STAGE(cur ^ 1, kb + 1);   // prefetch next tile
      const __bf16* Kb = Kl[cur];
      const __bf16* Vb = Vl[cur];
      if (kb * 64 <= q0 + 15) {                     // tile intersects rows
        bf16x8 kf[4][2];
#pragma unroll
        for (int ks = 0; ks < 4; ++ks)
#pragma unroll
          for (int h2 = 0; h2 < 2; ++h2) {
            const int p = r16 + ks * 16;
            const int ch = (g + 4 * h2) ^ (p & 7);
            kf[ks][h2] = *(const bf16x8*)&Kb[p * 64 + ch * 8];
          }
        const bool needmask = (kb * 64 + 63 > q0); // only diagonal tiles mask
        float svv[4][4];
        __builtin_amdgcn_s_setprio(1);
#pragma unroll
        for (int ks = 0; ks < 4; ++ks) {
          f32x4 sacc = {-12.f, -12.f, -12.f, -12.f};   // fixed max in C-init
          sacc = mfma16(kf[ks][0], qf[0], sacc);       // SWAPPED: S^T
          sacc = mfma16(kf[ks][1], qf[1], sacc);
#pragma unroll
          for (int r = 0; r < 4; ++r) svv[ks][r] = sacc[r];
        }
        __builtin_amdgcn_s_setprio(0);
        if (needmask) {
#pragma unroll
          for (int ks = 0; ks < 4; ++ks)
#pragma unroll
            for (int r = 0; r < 4; ++r) {
              int pg = kb * 64 + ks * 16 + g * 4 + r;  // kv (swapped)
              int qg = q0 + r16;                       // q  (swapped)
              if (pg > qg) svv[ks][r] = -1e30f;
            }
        }
        // exp2 + packed b64 store into P[q=r16][kv]: contiguous 4 per ks
#pragma unroll
        for (int ks = 0; ks < 4; ++ks) {
          bf16x4 pk;
#pragma unroll
          for (int r = 0; r < 4; ++r) {
            float p = fast_exp2(svv[ks][r]);
            l_q += p;
            pk[r] = (__bf16)p;
          }
          *(bf16x4*)&Pw[r16 * 72 + ks * 16 + g * 4] = pk;
        }
        bf16x8 pf0 = *(const bf16x8*)&Pw[r16 * 72 + g * 8];
        bf16x8 pf1 = *(const bf16x8*)&Pw[r16 * 72 + 32 + g * 8];
        __builtin_amdgcn_s_setprio(1);
#pragma unroll
        for (int nb = 0; nb < 4; ++nb) {
          const int d = r16 + nb * 16;
          const int ch0 = g ^ (d & 7), ch1 = (4 + g) ^ (d & 7);
          bf16x8 vf0 = *(const bf16x8*)&Vb[d * 64 + ch0 * 8];
          bf16x8 vf1 = *(const bf16x8*)&Vb[d * 64 + ch1 * 8];
          acc[nb] = mfma16(pf0, vf0, acc[nb]);
          acc[nb] = mfma16(pf1, vf1, acc[nb]);
        }
        __builtin_amdgcn_s_setprio(0);
      }
      asm volatile("s_waitcnt vmcnt(0)" ::: "memory");
      __syncthreads();
    }
    // epilogue: complete l over kv (sum the 4 g-groups), redistribute, store
    l_q += __shfl_xor(l_q, 16);
    l_q += __shfl_xor(l_q, 32);
    const float invq = 1.0f / l_q;
    float inv[4];
#pragma unroll
    for (int r = 0; r < 4; ++r) inv[r] = __shfl(invq, g * 4 + r);
#pragma unroll
    for (int nb = 0; nb < 4; ++nb)
#pragma unroll
      for (int r = 0; r < 4; ++r)
        O[(((size_t)b * SEQ + q0 + g * 4 + r) * HH + h) * HD + nb * 16 + r16] =
            (__bf16)(acc[nb][r] * inv[r]);
  }
}

// ---------------- launch ----------------

extern "C" void kernel_launch(void* const* d_in, const int* in_sizes, int n_in,
                              void* d_out, int out_size, void* d_ws, size_t ws_size,
                              hipStream_t stream) {
  const float* hidden = (const float*)d_in[0];
  const float* cosT   = (const float*)d_in[1];
  const float* sinT   = (const float*)d_in[2];
  const float* wq     = (const float*)d_in[3];
  const float* wk     = (const float*)d_in[4];
  const float* wv     = (const float*)d_in[5];
  const float* wo     = (const float*)d_in[6];
  const float* qw     = (const float*)d_in[7];
  const float* kw     = (const float*)d_in[8];
  float* out = (float*)d_out;
  char* ws = (char*)d_ws;

  // workspace layout (64 MB, lifetime-aliased):
  __bf16* Abf  = (__bf16*)(ws);                      // [0,16M) hidden bf16; later Ob
  __bf16* Ob   = Abf;
  __bf16* WT   = (__bf16*)(ws + (16u << 20));        // [16,28M) qkv weights^T
  __bf16* Qr   = (__bf16*)(ws + (28u << 20));        // [28,44M) Q roped (log2 domain)
  __bf16* Kr   = (__bf16*)(ws + (44u << 20));        // [44,48M) K roped
  __bf16* VT   = (__bf16*)(ws + (52u << 20));        // [52,56M) V transposed (direct)
  __bf16* WoT  = (__bf16*)(ws + (56u << 20));        // [56,64M)

  k_prep<<<18432, 256, 0, stream>>>(hidden, Abf, wq, wk, wv, wo, WT, WoT);

  // 8-phase 256^2 QKV GEMM: M=4096, N=3072 -> 16x12 = 192 blocks
  k_gemm8<1, __bf16><<<192, 512, 0, stream>>>(Abf, WT, (__bf16*)nullptr,
      NTOK, NQKV, DMODEL, cosT, sinT, qw, kw, Qr, Kr, VT);

  k_attn<<<dim3(512), 512, 0, stream>>>(Qr, Kr, VT, Ob);

  k_gemm3<0, float><<<512, 256, 0, stream>>>(Ob, WoT, out,
      NTOK, DMODEL, DMODEL);
}